// Round 4
// baseline (405.018 us; speedup 1.0000x reference)
//
#include <hip/hip_runtime.h>
#include <math.h>

#define NSEQ  4096
#define DDIM  64
#define GH    64
#define NORMC 0.35355339059327373f   /* 64^-0.25 */
#define EPSC  1e-4f

typedef __bf16 bf16x8 __attribute__((ext_vector_type(8)));
typedef unsigned short u16x8 __attribute__((ext_vector_type(8)));
typedef float f32x4 __attribute__((ext_vector_type(4)));

__device__ __forceinline__ unsigned enc_f(float f) {
    unsigned b = __float_as_uint(f);
    return (b & 0x80000000u) ? ~b : (b | 0x80000000u);
}
__device__ __forceinline__ float dec_f(unsigned u) {
    return (u & 0x80000000u) ? __uint_as_float(u & 0x7FFFFFFFu) : __uint_as_float(~u);
}
__device__ __forceinline__ void split_hl(float f, unsigned short& h, unsigned short& l) {
    unsigned u = __float_as_uint(f);
    unsigned hb = u & 0xffff0000u;
    h = (unsigned short)(hb >> 16);
    l = (unsigned short)(__float_as_uint(f - __uint_as_float(hb)) >> 16);
}
__device__ __forceinline__ bf16x8 ldfrag(const unsigned short* p) {
    return __builtin_bit_cast(bf16x8, *(const u16x8*)p);
}
__device__ __forceinline__ f32x4 zero4() { f32x4 z = {0.f, 0.f, 0.f, 0.f}; return z; }
__device__ __forceinline__ f32x4 mfma3(bf16x8 ah, bf16x8 al, bf16x8 bh, bf16x8 bl, f32x4 c) {
    c = __builtin_amdgcn_mfma_f32_16x16x32_bf16(ah, bh, c, 0, 0, 0);
    c = __builtin_amdgcn_mfma_f32_16x16x32_bf16(ah, bl, c, 0, 0, 0);
    c = __builtin_amdgcn_mfma_f32_16x16x32_bf16(al, bh, c, 0, 0, 0);
    return c;
}

// ================= Kernel A: K-side (swapped GEMM2, no W round-trip) =================
// GEMM1: dash[n][m] = K·(NORMC·P)^T  (A=K rows, B=P -> lane holds m=u*16+li, n=tt*16+4lg+r)
// exp in-place; GEMM2 swapped: ctx^T[e][m] = V^T · W, with contraction index n relabeled
// so the w registers feed the B-operand directly (kslot(n) = 8*((n>>2)&3) + 4*(n>>4) + (n&3)).
template<int NSLICE>
__global__ __launch_bounds__(256, 2)
void kernA(const float* __restrict__ kk, const float* __restrict__ vv,
           const float* __restrict__ proj, float* __restrict__ Apart,
           float* __restrict__ Aspart, float* __restrict__ Svpart,
           unsigned* __restrict__ mxk)
{
    const int slices = (NSLICE == 1) ? 16 : NSLICE;
    const int slice = blockIdx.x;
    const int g     = blockIdx.y;
    const int t     = threadIdx.x;
    const int lane  = t & 63;
    const int wq    = t >> 6;
    const int li    = lane & 15;
    const int lg    = lane >> 4;

    // 16KB arena: Khi | Klo | Vthi | Vtlo ; reused as f32 transpose buffer in epilogue
    __shared__ __align__(16) unsigned short KV[8192];
    __shared__ float diag[32];
    __shared__ float svred[4][64];
    __shared__ float mxred[4];
    unsigned short* Khi  = KV;
    unsigned short* Klo  = KV + 2048;
    unsigned short* Vthi = KV + 4096;
    unsigned short* Vtlo = KV + 6144;

    // P fragments (NORMC folded), per-wave m-quarter
    bf16x8 pfh[4][2], pfl[4][2];
#pragma unroll
    for (int u = 0; u < 4; u++)
#pragma unroll
    for (int s = 0; s < 2; s++) {
        const float* pr = proj + (size_t)(wq * 64 + u * 16 + li) * DDIM + s * 32 + lg * 8;
        u16x8 hh, ll;
#pragma unroll
        for (int j = 0; j < 8; j++) {
            unsigned short h, l;
            split_hl(NORMC * pr[j], h, l);
            hh[j] = h; ll[j] = l;
        }
        pfh[u][s] = __builtin_bit_cast(bf16x8, hh);
        pfl[u][s] = __builtin_bit_cast(bf16x8, ll);
    }

    f32x4 cacc[4][4];   // [u2 e-tile][u m-tile]: e=u2*16+4lg+r, m=u*16+li
#pragma unroll
    for (int a = 0; a < 4; a++)
#pragma unroll
    for (int b = 0; b < 4; b++) cacc[a][b] = zero4();
    float as_loc[4] = {0.f, 0.f, 0.f, 0.f};
    float sv8[8] = {0.f,0.f,0.f,0.f,0.f,0.f,0.f,0.f};
    float mloc = -1e30f;

    const int stg_n = t >> 3;
    const int stg_c = t & 7;
    const int rows_per = NSEQ / slices;
    const int r_begin = slice * rows_per;
    // scrambled k-slot for V^T staging (bijection on n in [0,32))
    const int vks = ((stg_n >> 2) & 3) * 8 + (stg_n >> 4) * 4 + (stg_n & 3);

    for (int r0 = r_begin; r0 < r_begin + rows_per; r0 += 32) {
        { // stage K planes (XOR swizzle) + diag
            const float4* kb = (const float4*)(kk + ((size_t)g * NSEQ + r0 + stg_n) * DDIM + stg_c * 8);
            float4 a0 = kb[0], a1 = kb[1];
            float sq = a0.x*a0.x + a0.y*a0.y + a0.z*a0.z + a0.w*a0.w
                     + a1.x*a1.x + a1.y*a1.y + a1.z*a1.z + a1.w*a1.w;
            sq += __shfl_xor(sq, 1); sq += __shfl_xor(sq, 2); sq += __shfl_xor(sq, 4);
            if (stg_c == 0) diag[stg_n] = 0.0625f * sq;
            u16x8 h8, l8;
            {
                unsigned short h, l;
                split_hl(a0.x,h,l); h8[0]=h; l8[0]=l;
                split_hl(a0.y,h,l); h8[1]=h; l8[1]=l;
                split_hl(a0.z,h,l); h8[2]=h; l8[2]=l;
                split_hl(a0.w,h,l); h8[3]=h; l8[3]=l;
                split_hl(a1.x,h,l); h8[4]=h; l8[4]=l;
                split_hl(a1.y,h,l); h8[5]=h; l8[5]=l;
                split_hl(a1.z,h,l); h8[6]=h; l8[6]=l;
                split_hl(a1.w,h,l); h8[7]=h; l8[7]=l;
            }
            int idx = stg_n * 64 + (stg_c ^ (stg_n & 7)) * 8;
            *(u16x8*)&Khi[idx] = h8;
            *(u16x8*)&Klo[idx] = l8;
            // stage V^T planes at scrambled kslot + Sv accum
            const float4* vb = (const float4*)(vv + ((size_t)g * NSEQ + r0 + stg_n) * DDIM + stg_c * 8);
            float4 b0 = vb[0], b1 = vb[1];
            float ve[8] = {b0.x,b0.y,b0.z,b0.w,b1.x,b1.y,b1.z,b1.w};
#pragma unroll
            for (int j = 0; j < 8; j++) {
                sv8[j] += ve[j];
                unsigned short h, l;
                split_hl(ve[j], h, l);
                int e = stg_c * 8 + j;
                Vthi[e * 32 + vks] = h;
                Vtlo[e * 32 + vks] = l;
            }
        }
        __syncthreads();
        // GEMM1: dash
        f32x4 dacc[2][4];
#pragma unroll
        for (int tt = 0; tt < 2; tt++)
#pragma unroll
        for (int u = 0; u < 4; u++) dacc[tt][u] = zero4();
#pragma unroll
        for (int tt = 0; tt < 2; tt++)
#pragma unroll
        for (int s = 0; s < 2; s++) {
            int idx = (tt * 16 + li) * 64 + ((s * 4 + lg) ^ (li & 7)) * 8;
            bf16x8 ah = ldfrag(&Khi[idx]);
            bf16x8 al = ldfrag(&Klo[idx]);
#pragma unroll
            for (int u = 0; u < 4; u++) dacc[tt][u] = mfma3(ah, al, pfh[u][s], pfl[u][s], dacc[tt][u]);
        }
        // exp in-place (w replaces dash)
#pragma unroll
        for (int tt = 0; tt < 2; tt++)
#pragma unroll
        for (int u = 0; u < 4; u++)
#pragma unroll
        for (int r = 0; r < 4; r++) {
            float dash = dacc[tt][u][r];
            mloc = fmaxf(mloc, dash);
            float w = __expf(dash - diag[tt * 16 + lg * 4 + r]);
            as_loc[u] += w;
            dacc[tt][u][r] = w;
        }
        // B-frags by pure register relabel: kslot jj -> (tt=jj>>2, r=jj&3)
        u16x8 whh[4], wll[4];
#pragma unroll
        for (int u = 0; u < 4; u++)
#pragma unroll
        for (int jj = 0; jj < 8; jj++) {
            unsigned short h, l;
            split_hl(dacc[jj >> 2][u][jj & 3], h, l);
            whh[u][jj] = h; wll[u][jj] = l;
        }
        // A-frags: V^T planes, b128
        bf16x8 avh[4], avl[4];
#pragma unroll
        for (int u2 = 0; u2 < 4; u2++) {
            avh[u2] = ldfrag(&Vthi[(u2 * 16 + li) * 32 + lg * 8]);
            avl[u2] = ldfrag(&Vtlo[(u2 * 16 + li) * 32 + lg * 8]);
        }
#pragma unroll
        for (int u = 0; u < 4; u++) {
            bf16x8 bh = __builtin_bit_cast(bf16x8, whh[u]);
            bf16x8 bl = __builtin_bit_cast(bf16x8, wll[u]);
#pragma unroll
            for (int u2 = 0; u2 < 4; u2++)
                cacc[u2][u] = mfma3(avh[u2], avl[u2], bh, bl, cacc[u2][u]);
        }
        __syncthreads();
    }

    // epilogue scalars
#pragma unroll
    for (int j = 0; j < 8; j++) {
        float s = sv8[j];
        s += __shfl_xor(s, 8); s += __shfl_xor(s, 16); s += __shfl_xor(s, 32);
        sv8[j] = s;
    }
    if (lane < 8) {
#pragma unroll
        for (int j = 0; j < 8; j++) svred[wq][lane * 8 + j] = sv8[j];
    }
    float mm = mloc;
#pragma unroll
    for (int off = 32; off >= 1; off >>= 1) mm = fmaxf(mm, __shfl_xor(mm, off));
    if (lane == 0) mxred[wq] = mm;
#pragma unroll
    for (int u = 0; u < 4; u++) {
        float a = as_loc[u];
        a += __shfl_xor(a, 16); a += __shfl_xor(a, 32);
        as_loc[u] = a;
    }
    __syncthreads();
    if (t == 0) {
        float m4 = fmaxf(fmaxf(mxred[0], mxred[1]), fmaxf(mxred[2], mxred[3]));
        atomicMax(mxk + g, enc_f(m4));
    }
    if (t < 64) {
        float s = svred[0][t] + svred[1][t] + svred[2][t] + svred[3][t];
        if (NSLICE == 1) atomicAdd(&Svpart[(size_t)g * 64 + t], s);
        else             Svpart[((size_t)g * NSLICE + slice) * 64 + t] = s;
    }
    if (lane < 16) {
#pragma unroll
        for (int u = 0; u < 4; u++) {
            int m = wq * 64 + u * 16 + lane;
            if (NSLICE == 1) atomicAdd(&Aspart[(size_t)g * 256 + m], as_loc[u]);
            else             Aspart[((size_t)g * NSLICE + slice) * 256 + m] = as_loc[u];
        }
    }
    // ctx partial: transpose cacc through per-wave arena quarter, coalesced store
    float* tb = (float*)KV + wq * 1024;   // [16 m][64 e] f32, XOR-swizzled granules
    float* Ad = (NSLICE == 1) ? (Apart + (size_t)g * 16384)
                              : (Apart + ((size_t)g * NSLICE + slice) * 16384);
    for (int u = 0; u < 4; u++) {
#pragma unroll
        for (int u2 = 0; u2 < 4; u2++)
#pragma unroll
        for (int r = 0; r < 4; r++)
            tb[li * 64 + ((((u2 << 2) | lg) ^ (li & 7)) << 2) + r] = cacc[u2][u][r];
#pragma unroll
        for (int j = 0; j < 4; j++) {
            int row16 = j * 4 + lg;
            int swz = li ^ (row16 & 7);
            f32x4 val = *(const f32x4*)&tb[row16 * 64 + swz * 4];
            float* dst = Ad + (wq * 64 + u * 16) * 64 + j * 256 + lane * 4;
            if (NSLICE == 1) {
                atomicAdd(dst + 0, val[0]); atomicAdd(dst + 1, val[1]);
                atomicAdd(dst + 2, val[2]); atomicAdd(dst + 3, val[3]);
            } else {
                *(f32x4*)dst = val;
            }
        }
    }
}

// ================= Kernel B: reduce partials (parallel) =================
__global__ __launch_bounds__(256)
void kernB(const float* __restrict__ Apart, const float* __restrict__ Aspart,
           const float* __restrict__ Svpart, const unsigned* __restrict__ mxk,
           float* __restrict__ ctx, float* __restrict__ ksum, int nslice)
{
    const int b = blockIdx.x;   // 0..15
    const int g = blockIdx.y;
    const int t = threadIdx.x;
    __shared__ float svh[64];
    float emx = __expf(-dec_f(mxk[g]));
    if (t < 64) {
        float s = 0.f;
        for (int sb = 0; sb < nslice; sb++) s += Svpart[((size_t)g * nslice + sb) * 64 + t];
        svh[t] = s;
    }
    if (b == 0) {
        float as_s = 0.f;
        for (int sb = 0; sb < nslice; sb++) as_s += Aspart[((size_t)g * nslice + sb) * 256 + t];
        ksum[(size_t)g * 256 + t] = emx * as_s + EPSC * (float)NSEQ;
    }
    __syncthreads();
    int idx4 = b * 256 + t;
    const f32x4* Ap = (const f32x4*)Apart;
    f32x4 s = zero4();
    for (int sb = 0; sb < nslice; sb++) s += Ap[((size_t)g * nslice + sb) * 4096 + idx4];
    int e0 = (idx4 * 4) & 63;
    f32x4 o;
    o[0] = emx * s[0] + EPSC * svh[e0];
    o[1] = emx * s[1] + EPSC * svh[e0 + 1];
    o[2] = emx * s[2] + EPSC * svh[e0 + 2];
    o[3] = emx * s[3] + EPSC * svh[e0 + 3];
    ((f32x4*)ctx)[(size_t)g * 4096 + idx4] = o;
}

// ================= Kernel C: Q-side + output (LDS-diet, 4 barriers/tile) =================
__global__ __launch_bounds__(256, 4)
void kernC(const float* __restrict__ qq, const float* __restrict__ proj,
           const float* __restrict__ ctx, const float* __restrict__ ksum,
           float* __restrict__ outp)
{
    const int slice = blockIdx.x;   // 0..15
    const int g     = blockIdx.y;
    const int t     = threadIdx.x;
    const int lane  = t & 63;
    const int wq    = t >> 6;
    const int li    = lane & 15;
    const int lg    = lane >> 4;

    // per-wave 8704B buffers; Q staging planes live in wbuf[0] (time-disjoint)
    __shared__ __align__(16) unsigned wbuf[4][2176];
    __shared__ float diag[32];
    __shared__ float rmax4[4][32];
    __shared__ float denp[4][32];

    unsigned short* Qhi = (unsigned short*)&wbuf[0][0];
    unsigned short* Qlo = Qhi + 2048;
    unsigned short* qh  = (unsigned short*)&wbuf[wq][0];
    unsigned short* ql  = qh + 2048;
    float* ob = (float*)&wbuf[wq][0];   // [32][65] f32

    bf16x8 pfh[4][2], pfl[4][2];
#pragma unroll
    for (int u = 0; u < 4; u++)
#pragma unroll
    for (int s = 0; s < 2; s++) {
        const float* pr = proj + (size_t)(wq * 64 + u * 16 + li) * DDIM + s * 32 + lg * 8;
        u16x8 hh, ll;
#pragma unroll
        for (int j = 0; j < 8; j++) {
            unsigned short h, l;
            split_hl(NORMC * pr[j], h, l);
            hh[j] = h; ll[j] = l;
        }
        pfh[u][s] = __builtin_bit_cast(bf16x8, hh);
        pfl[u][s] = __builtin_bit_cast(bf16x8, ll);
    }
    bf16x8 cfh[4][2], cfl[4][2];
#pragma unroll
    for (int u2 = 0; u2 < 4; u2++)
#pragma unroll
    for (int s = 0; s < 2; s++) {
        u16x8 hh, ll;
#pragma unroll
        for (int j = 0; j < 8; j++) {
            unsigned short h, l;
            split_hl(ctx[((size_t)g * 256 + wq * 64 + s * 32 + lg * 8 + j) * 64 + u2 * 16 + li], h, l);
            hh[j] = h; ll[j] = l;
        }
        cfh[u2][s] = __builtin_bit_cast(bf16x8, hh);
        cfl[u2][s] = __builtin_bit_cast(bf16x8, ll);
    }
    float ksm[4];
#pragma unroll
    for (int u = 0; u < 4; u++) ksm[u] = ksum[(size_t)g * 256 + wq * 64 + u * 16 + li];

    const int stg_n = t >> 3;
    const int stg_c = t & 7;
    const int r_begin = slice * (NSEQ / 16);

    for (int r0 = r_begin; r0 < r_begin + NSEQ / 16; r0 += 32) {
        { // stage Q planes + diag
            const float4* qb = (const float4*)(qq + ((size_t)g * NSEQ + r0 + stg_n) * DDIM + stg_c * 8);
            float4 a0 = qb[0], a1 = qb[1];
            float sq = a0.x*a0.x + a0.y*a0.y + a0.z*a0.z + a0.w*a0.w
                     + a1.x*a1.x + a1.y*a1.y + a1.z*a1.z + a1.w*a1.w;
            sq += __shfl_xor(sq, 1); sq += __shfl_xor(sq, 2); sq += __shfl_xor(sq, 4);
            if (stg_c == 0) diag[stg_n] = 0.0625f * sq;
            u16x8 h8, l8;
            {
                unsigned short h, l;
                split_hl(a0.x,h,l); h8[0]=h; l8[0]=l;
                split_hl(a0.y,h,l); h8[1]=h; l8[1]=l;
                split_hl(a0.z,h,l); h8[2]=h; l8[2]=l;
                split_hl(a0.w,h,l); h8[3]=h; l8[3]=l;
                split_hl(a1.x,h,l); h8[4]=h; l8[4]=l;
                split_hl(a1.y,h,l); h8[5]=h; l8[5]=l;
                split_hl(a1.z,h,l); h8[6]=h; l8[6]=l;
                split_hl(a1.w,h,l); h8[7]=h; l8[7]=l;
            }
            int idx = stg_n * 64 + (stg_c ^ (stg_n & 7)) * 8;
            *(u16x8*)&Qhi[idx] = h8;
            *(u16x8*)&Qlo[idx] = l8;
        }
        __syncthreads();   // A
        // GEMM1: dash_q
        f32x4 dacc[2][4];
#pragma unroll
        for (int tt = 0; tt < 2; tt++)
#pragma unroll
        for (int u = 0; u < 4; u++) dacc[tt][u] = zero4();
#pragma unroll
        for (int tt = 0; tt < 2; tt++)
#pragma unroll
        for (int s = 0; s < 2; s++) {
            int idx = (tt * 16 + li) * 64 + ((s * 4 + lg) ^ (li & 7)) * 8;
            bf16x8 ah = ldfrag(&Qhi[idx]);
            bf16x8 al = ldfrag(&Qlo[idx]);
#pragma unroll
            for (int u = 0; u < 4; u++) dacc[tt][u] = mfma3(ah, al, pfh[u][s], pfl[u][s], dacc[tt][u]);
        }
        // row max over m (wave partials)
#pragma unroll
        for (int tt = 0; tt < 2; tt++)
#pragma unroll
        for (int r = 0; r < 4; r++) {
            float v = fmaxf(fmaxf(dacc[tt][0][r], dacc[tt][1][r]),
                            fmaxf(dacc[tt][2][r], dacc[tt][3][r]));
            v = fmaxf(v, __shfl_xor(v, 1));
            v = fmaxf(v, __shfl_xor(v, 2));
            v = fmaxf(v, __shfl_xor(v, 4));
            v = fmaxf(v, __shfl_xor(v, 8));
            if (li == 0) rmax4[wq][tt * 16 + lg * 4 + r] = v;
        }
        __syncthreads();   // B
        // qp (inline comb), den partials, qp planes
        float dl[2][4] = {{0.f,0.f,0.f,0.f},{0.f,0.f,0.f,0.f}};
#pragma unroll
        for (int tt = 0; tt < 2; tt++) {
            float cb[4];
#pragma unroll
            for (int r = 0; r < 4; r++) {
                int n = tt * 16 + lg * 4 + r;
                cb[r] = diag[n] + fmaxf(fmaxf(rmax4[0][n], rmax4[1][n]),
                                        fmaxf(rmax4[2][n], rmax4[3][n]));
            }
#pragma unroll
            for (int u = 0; u < 4; u++)
#pragma unroll
            for (int r = 0; r < 4; r++) {
                float qp = __expf(dacc[tt][u][r] - cb[r]) + EPSC;
                dl[tt][r] += qp * ksm[u];
                int n = tt * 16 + lg * 4 + r;
                int m = u * 16 + li;
                int idx = n * 64 + (((m >> 3) ^ (n & 7)) << 3) + (m & 7);
                unsigned short h, l;
                split_hl(qp, h, l);
                qh[idx] = h;
                ql[idx] = l;
            }
        }
#pragma unroll
        for (int tt = 0; tt < 2; tt++)
#pragma unroll
        for (int r = 0; r < 4; r++) {
            float v = dl[tt][r];
            v += __shfl_xor(v, 1); v += __shfl_xor(v, 2);
            v += __shfl_xor(v, 4); v += __shfl_xor(v, 8);
            if (li == 0) denp[wq][tt * 16 + lg * 4 + r] = v;
        }
        // GEMM3 (reads own wave's qp planes; in-wave LDS ordering)
        f32x4 oacc[2][4];
#pragma unroll
        for (int tt = 0; tt < 2; tt++)
#pragma unroll
        for (int u2 = 0; u2 < 4; u2++) oacc[tt][u2] = zero4();
#pragma unroll
        for (int s = 0; s < 2; s++)
#pragma unroll
        for (int tt = 0; tt < 2; tt++) {
            int n = tt * 16 + li;
            int idx = n * 64 + ((s * 4 + lg) ^ (n & 7)) * 8;
            bf16x8 ah = ldfrag(&qh[idx]);
            bf16x8 al = ldfrag(&ql[idx]);
#pragma unroll
            for (int u2 = 0; u2 < 4; u2++)
                oacc[tt][u2] = mfma3(ah, al, cfh[u2][s], cfl[u2][s], oacc[tt][u2]);
        }
        // out partials -> own wave buffer (f32 [32][65])
#pragma unroll
        for (int tt = 0; tt < 2; tt++)
#pragma unroll
        for (int u2 = 0; u2 < 4; u2++)
#pragma unroll
        for (int r = 0; r < 4; r++)
            ob[(tt * 16 + lg * 4 + r) * 65 + u2 * 16 + li] = oacc[tt][u2][r];
        __syncthreads();   // C
        { // combine 4 wave partials, divide, store
            float den = denp[0][stg_n] + denp[1][stg_n] + denp[2][stg_n] + denp[3][stg_n];
            float dinv = 1.0f / den;
            float o[8];
#pragma unroll
            for (int j = 0; j < 8; j++) {
                float s = 0.f;
#pragma unroll
                for (int w4 = 0; w4 < 4; w4++)
                    s += ((const float*)&wbuf[w4][0])[stg_n * 65 + stg_c * 8 + j];
                o[j] = s * dinv;
            }
            float4 o0 = {o[0], o[1], o[2], o[3]};
            float4 o1 = {o[4], o[5], o[6], o[7]};
            float* op = outp + ((size_t)g * NSEQ + r0 + stg_n) * DDIM + stg_c * 8;
            ((float4*)op)[0] = o0;
            ((float4*)op)[1] = o1;
        }
        __syncthreads();   // D
    }
}

extern "C" void kernel_launch(void* const* d_in, const int* in_sizes, int n_in,
                              void* d_out, int out_size, void* d_ws, size_t ws_size,
                              hipStream_t stream)
{
    const float* q    = (const float*)d_in[0];
    const float* k    = (const float*)d_in[1];
    const float* v    = (const float*)d_in[2];
    const float* proj = (const float*)d_in[3];
    float* outp = (float*)d_out;

    size_t per_ns = (size_t)GH * 16384 + (size_t)GH * 256 + (size_t)GH * 64;
    size_t fixed  = (size_t)GH * 16384 + (size_t)GH * 256;
    size_t need16 = 256 + 4 * (16 * per_ns + fixed);
    size_t need8  = 256 + 4 * (8 * per_ns + fixed);
    int ns = (ws_size >= need16) ? 16 : ((ws_size >= need8) ? 8 : 1);

    unsigned* mxk = (unsigned*)d_ws;
    float* Apart  = (float*)((char*)d_ws + 256);
    float* Aspart = Apart  + (size_t)GH * ns * 16384;
    float* Svpart = Aspart + (size_t)GH * ns * 256;
    float* ctx    = Svpart + (size_t)GH * ns * 64;
    float* ksum   = ctx    + (size_t)GH * 16384;

    if (ns == 16) {
        hipMemsetAsync(d_ws, 0, 256, stream);
        kernA<16><<<dim3(16, GH), 256, 0, stream>>>(k, v, proj, Apart, Aspart, Svpart, mxk);
    } else if (ns == 8) {
        hipMemsetAsync(d_ws, 0, 256, stream);
        kernA<8><<<dim3(8, GH), 256, 0, stream>>>(k, v, proj, Apart, Aspart, Svpart, mxk);
    } else {
        hipMemsetAsync(d_ws, 0, 256 + 4 * per_ns, stream);
        kernA<1><<<dim3(16, GH), 256, 0, stream>>>(k, v, proj, Apart, Aspart, Svpart, mxk);
    }
    kernB<<<dim3(16, GH), 256, 0, stream>>>(Apart, Aspart, Svpart, mxk, ctx, ksum, ns);
    kernC<<<dim3(16, GH), 256, 0, stream>>>(q, proj, ctx, ksum, outp);
}

// Round 5
// 208.617 us; speedup vs baseline: 1.9414x; 1.9414x over previous
//
#include <hip/hip_runtime.h>
#include <math.h>

#define NSEQ  4096
#define DDIM  64
#define GH    64
#define NORMC 0.35355339059327373f   /* 64^-0.25 */
#define EPSC  1e-4f

typedef __bf16 bf16x8 __attribute__((ext_vector_type(8)));
typedef unsigned short u16x8 __attribute__((ext_vector_type(8)));
typedef float f32x4 __attribute__((ext_vector_type(4)));

__device__ __forceinline__ unsigned enc_f(float f) {
    unsigned b = __float_as_uint(f);
    return (b & 0x80000000u) ? ~b : (b | 0x80000000u);
}
__device__ __forceinline__ float dec_f(unsigned u) {
    return (u & 0x80000000u) ? __uint_as_float(u & 0x7FFFFFFFu) : __uint_as_float(~u);
}
__device__ __forceinline__ void split_hl(float f, unsigned short& h, unsigned short& l) {
    unsigned u = __float_as_uint(f);
    unsigned hb = u & 0xffff0000u;
    h = (unsigned short)(hb >> 16);
    l = (unsigned short)(__float_as_uint(f - __uint_as_float(hb)) >> 16);
}
// round-to-nearest bf16 (positive normal floats)
__device__ __forceinline__ unsigned short rne16(float f) {
    return (unsigned short)((__float_as_uint(f) + 0x8000u) >> 16);
}
__device__ __forceinline__ bf16x8 ldfrag(const unsigned short* p) {
    return __builtin_bit_cast(bf16x8, *(const u16x8*)p);
}
__device__ __forceinline__ f32x4 zero4() { f32x4 z = {0.f, 0.f, 0.f, 0.f}; return z; }
__device__ __forceinline__ f32x4 mfma3(bf16x8 ah, bf16x8 al, bf16x8 bh, bf16x8 bl, f32x4 c) {
    c = __builtin_amdgcn_mfma_f32_16x16x32_bf16(ah, bh, c, 0, 0, 0);
    c = __builtin_amdgcn_mfma_f32_16x16x32_bf16(ah, bl, c, 0, 0, 0);
    c = __builtin_amdgcn_mfma_f32_16x16x32_bf16(al, bh, c, 0, 0, 0);
    return c;
}

// ================= Kernel A: K-side, 1 barrier/tile, dbuf staging =================
template<int NSLICE>
__global__ __launch_bounds__(256, 2)
void kernA(const float* __restrict__ kk, const float* __restrict__ vv,
           const float* __restrict__ proj, float* __restrict__ Apart,
           float* __restrict__ Aspart, float* __restrict__ Svpart,
           unsigned* __restrict__ mxk)
{
    const int slice = blockIdx.x;     // 0..7
    const int g     = blockIdx.y;
    const int t     = threadIdx.x;
    const int lane  = t & 63;
    const int wq    = t >> 6;
    const int li    = lane & 15;
    const int lg    = lane >> 4;

    // 32KB: 2 bufs x (Khi 2048 | Klo 2048 | Vthi 2048 | Vtlo 2048) u16
    __shared__ __align__(16) unsigned short ARENA[16384];
    __shared__ float diag[2][32];
    __shared__ float svred[4][64];
    __shared__ float mxred[4];

    // P fragments (NORMC folded), per-wave m-quarter
    bf16x8 pfh[4][2], pfl[4][2];
#pragma unroll
    for (int u = 0; u < 4; u++)
#pragma unroll
    for (int s = 0; s < 2; s++) {
        const float* pr = proj + (size_t)(wq * 64 + u * 16 + li) * DDIM + s * 32 + lg * 8;
        u16x8 hh, ll;
#pragma unroll
        for (int j = 0; j < 8; j++) {
            unsigned short h, l;
            split_hl(NORMC * pr[j], h, l);
            hh[j] = h; ll[j] = l;
        }
        pfh[u][s] = __builtin_bit_cast(bf16x8, hh);
        pfl[u][s] = __builtin_bit_cast(bf16x8, ll);
    }

    f32x4 cacc[4][4];   // [u2 e-tile][u m-tile]
#pragma unroll
    for (int a = 0; a < 4; a++)
#pragma unroll
    for (int b = 0; b < 4; b++) cacc[a][b] = zero4();
    float as_loc[4] = {0.f, 0.f, 0.f, 0.f};
    float sv8[8] = {0.f,0.f,0.f,0.f,0.f,0.f,0.f,0.f};
    float mloc = -1e30f;

    const int stg_n = t >> 3;
    const int stg_c = t & 7;
    const int rows_per = NSEQ / 8;    // 512
    const int r_begin = slice * rows_per;
    const int vks = ((stg_n >> 2) & 3) * 8 + (stg_n >> 4) * 4 + (stg_n & 3);

    float4 ka0, ka1, va0, va1;
    auto load_tile = [&](int r0) {
        const float4* kb = (const float4*)(kk + ((size_t)g * NSEQ + r0 + stg_n) * DDIM + stg_c * 8);
        ka0 = kb[0]; ka1 = kb[1];
        const float4* vb = (const float4*)(vv + ((size_t)g * NSEQ + r0 + stg_n) * DDIM + stg_c * 8);
        va0 = vb[0]; va1 = vb[1];
    };
    auto stage_tile = [&](int b) {
        unsigned short* Khi  = ARENA + b * 8192;
        unsigned short* Klo  = Khi + 2048;
        unsigned short* Vthi = Khi + 4096;
        unsigned short* Vtlo = Khi + 6144;
        float ke[8] = {ka0.x,ka0.y,ka0.z,ka0.w,ka1.x,ka1.y,ka1.z,ka1.w};
        float sq = 0.f;
#pragma unroll
        for (int j = 0; j < 8; j++) sq += ke[j] * ke[j];
        sq += __shfl_xor(sq, 1); sq += __shfl_xor(sq, 2); sq += __shfl_xor(sq, 4);
        if (stg_c == 0) diag[b][stg_n] = 0.0625f * sq;
        u16x8 h8, l8;
#pragma unroll
        for (int j = 0; j < 8; j++) {
            unsigned short h, l;
            split_hl(ke[j], h, l);
            h8[j] = h; l8[j] = l;
        }
        int idx = stg_n * 64 + (stg_c ^ (stg_n & 7)) * 8;
        *(u16x8*)&Khi[idx] = h8;
        *(u16x8*)&Klo[idx] = l8;
        float ve[8] = {va0.x,va0.y,va0.z,va0.w,va1.x,va1.y,va1.z,va1.w};
#pragma unroll
        for (int j = 0; j < 8; j++) {
            sv8[j] += ve[j];
            unsigned short h, l;
            split_hl(ve[j], h, l);
            int e = stg_c * 8 + j;
            int slot = vks ^ (((e >> 1) & 3) << 3);
            Vthi[e * 32 + slot] = h;
            Vtlo[e * 32 + slot] = l;
        }
    };

    load_tile(r_begin);
    stage_tile(0);
    __syncthreads();
    int cur = 0;
    const int NT = rows_per / 32;   // 16
    for (int it = 0; it < NT; ++it) {
        if (it + 1 < NT) load_tile(r_begin + (it + 1) * 32);
        const unsigned short* Khi  = ARENA + cur * 8192;
        const unsigned short* Klo  = Khi + 2048;
        const unsigned short* Vthi = Khi + 4096;
        const unsigned short* Vtlo = Khi + 6144;
        // GEMM1: dash = K · P^T
        f32x4 dacc[2][4];
#pragma unroll
        for (int tt = 0; tt < 2; tt++)
#pragma unroll
        for (int u = 0; u < 4; u++) dacc[tt][u] = zero4();
#pragma unroll
        for (int tt = 0; tt < 2; tt++)
#pragma unroll
        for (int s = 0; s < 2; s++) {
            int idx = (tt * 16 + li) * 64 + ((s * 4 + lg) ^ (li & 7)) * 8;
            bf16x8 ah = ldfrag(&Khi[idx]);
            bf16x8 al = ldfrag(&Klo[idx]);
#pragma unroll
            for (int u = 0; u < 4; u++) dacc[tt][u] = mfma3(ah, al, pfh[u][s], pfl[u][s], dacc[tt][u]);
        }
        // exp -> single-bf16 w (relabel to B-frag k-slots); As from rounded value
        u16x8 whh[4];
#pragma unroll
        for (int tt = 0; tt < 2; tt++)
#pragma unroll
        for (int u = 0; u < 4; u++)
#pragma unroll
        for (int r = 0; r < 4; r++) {
            float dash = dacc[tt][u][r];
            mloc = fmaxf(mloc, dash);
            float w = __expf(dash - diag[cur][tt * 16 + lg * 4 + r]);
            unsigned short hb = rne16(w);
            whh[u][tt * 4 + r] = hb;
            as_loc[u] += __uint_as_float((unsigned)hb << 16);
        }
        // A-frags: V^T planes
        bf16x8 avh[4], avl[4];
#pragma unroll
        for (int u2 = 0; u2 < 4; u2++) {
            int row = u2 * 16 + li;
            int slot = (lg ^ ((li >> 1) & 3)) * 8;
            avh[u2] = ldfrag(&Vthi[row * 32 + slot]);
            avl[u2] = ldfrag(&Vtlo[row * 32 + slot]);
        }
        // GEMM2: ctx^T += V^T · W  (2 mfma per tile-pair)
#pragma unroll
        for (int u = 0; u < 4; u++) {
            bf16x8 b = __builtin_bit_cast(bf16x8, whh[u]);
#pragma unroll
            for (int u2 = 0; u2 < 4; u2++) {
                cacc[u2][u] = __builtin_amdgcn_mfma_f32_16x16x32_bf16(avh[u2], b, cacc[u2][u], 0, 0, 0);
                cacc[u2][u] = __builtin_amdgcn_mfma_f32_16x16x32_bf16(avl[u2], b, cacc[u2][u], 0, 0, 0);
            }
        }
        if (it + 1 < NT) stage_tile(cur ^ 1);
        __syncthreads();
        cur ^= 1;
    }

    // epilogue scalars
#pragma unroll
    for (int j = 0; j < 8; j++) {
        float s = sv8[j];
        s += __shfl_xor(s, 8); s += __shfl_xor(s, 16); s += __shfl_xor(s, 32);
        sv8[j] = s;
    }
    if (lane < 8) {
#pragma unroll
        for (int j = 0; j < 8; j++) svred[wq][lane * 8 + j] = sv8[j];
    }
    float mm = mloc;
#pragma unroll
    for (int off = 32; off >= 1; off >>= 1) mm = fmaxf(mm, __shfl_xor(mm, off));
    if (lane == 0) mxred[wq] = mm;
#pragma unroll
    for (int u = 0; u < 4; u++) {
        float a = as_loc[u];
        a += __shfl_xor(a, 16); a += __shfl_xor(a, 32);
        as_loc[u] = a;
    }
    __syncthreads();
    if (t == 0) {
        float m4 = fmaxf(fmaxf(mxred[0], mxred[1]), fmaxf(mxred[2], mxred[3]));
        atomicMax(mxk + g, enc_f(m4));
    }
    if (t < 64) {
        float s = svred[0][t] + svred[1][t] + svred[2][t] + svred[3][t];
        if (NSLICE == 1) atomicAdd(&Svpart[(size_t)g * 64 + t], s);
        else             Svpart[((size_t)g * NSLICE + slice) * 64 + t] = s;
    }
    if (lane < 16) {
#pragma unroll
        for (int u = 0; u < 4; u++) {
            int m = wq * 64 + u * 16 + lane;
            if (NSLICE == 1) atomicAdd(&Aspart[(size_t)g * 256 + m], as_loc[u]);
            else             Aspart[((size_t)g * NSLICE + slice) * 256 + m] = as_loc[u];
        }
    }
    // ctx partial: transpose cacc through per-wave arena quarter, coalesced stores
    float* tb = (float*)ARENA + wq * 1024;   // [16 m][64 e] f32, XOR-swizzled granules
    float* Ad = (NSLICE == 1) ? (Apart + (size_t)g * 16384)
                              : (Apart + ((size_t)g * NSLICE + slice) * 16384);
    for (int u = 0; u < 4; u++) {
#pragma unroll
        for (int u2 = 0; u2 < 4; u2++)
#pragma unroll
        for (int r = 0; r < 4; r++)
            tb[li * 64 + ((((u2 << 2) | lg) ^ (li & 7)) << 2) + r] = cacc[u2][u][r];
#pragma unroll
        for (int j = 0; j < 4; j++) {
            int row16 = j * 4 + lg;
            int swz = li ^ (row16 & 7);
            f32x4 val = *(const f32x4*)&tb[row16 * 64 + swz * 4];
            float* dst = Ad + (wq * 64 + u * 16) * 64 + j * 256 + lane * 4;
            if (NSLICE == 1) {
                atomicAdd(dst + 0, val[0]); atomicAdd(dst + 1, val[1]);
                atomicAdd(dst + 2, val[2]); atomicAdd(dst + 3, val[3]);
            } else {
                *(f32x4*)dst = val;
            }
        }
    }
}

// ================= Kernel B: reduce partials (parallel) =================
__global__ __launch_bounds__(256)
void kernB(const float* __restrict__ Apart, const float* __restrict__ Aspart,
           const float* __restrict__ Svpart, const unsigned* __restrict__ mxk,
           float* __restrict__ ctx, float* __restrict__ ksum, int nslice)
{
    const int b = blockIdx.x;   // 0..15
    const int g = blockIdx.y;
    const int t = threadIdx.x;
    __shared__ float svh[64];
    float emx = __expf(-dec_f(mxk[g]));
    if (t < 64) {
        float s = 0.f;
        for (int sb = 0; sb < nslice; sb++) s += Svpart[((size_t)g * nslice + sb) * 64 + t];
        svh[t] = s;
    }
    if (b == 0) {
        float as_s = 0.f;
        for (int sb = 0; sb < nslice; sb++) as_s += Aspart[((size_t)g * nslice + sb) * 256 + t];
        ksum[(size_t)g * 256 + t] = emx * as_s + EPSC * (float)NSEQ;
    }
    __syncthreads();
    int idx4 = b * 256 + t;
    const f32x4* Ap = (const f32x4*)Apart;
    f32x4 s = zero4();
    for (int sb = 0; sb < nslice; sb++) s += Ap[((size_t)g * nslice + sb) * 4096 + idx4];
    int e0 = (idx4 * 4) & 63;
    f32x4 o;
    o[0] = emx * s[0] + EPSC * svh[e0];
    o[1] = emx * s[1] + EPSC * svh[e0 + 1];
    o[2] = emx * s[2] + EPSC * svh[e0 + 2];
    o[3] = emx * s[3] + EPSC * svh[e0 + 3];
    ((f32x4*)ctx)[(size_t)g * 4096 + idx4] = o;
}

// ================= Kernel C: Q-side, swapped GEMM3, 2 barriers/tile =================
__global__ __launch_bounds__(256, 2)
void kernC(const float* __restrict__ qq, const float* __restrict__ proj,
           const float* __restrict__ ctx, const float* __restrict__ ksum,
           float* __restrict__ outp)
{
    const int slice = blockIdx.x;   // 0..15
    const int g     = blockIdx.y;
    const int t     = threadIdx.x;
    const int lane  = t & 63;
    const int wq    = t >> 6;
    const int li    = lane & 15;
    const int lg    = lane >> 4;

    __shared__ __align__(16) unsigned short QAR[2][4096];  // per buf: Qhi | Qlo
    __shared__ __align__(16) unsigned short qph[8192];     // [n=32][m 256] bf16, granule-swizzled
    __shared__ float diag[2][32];
    __shared__ float rmax4[4][32];
    __shared__ float denp[4][32];

    // P fragments for GEMM1 (m-quarter wq)
    bf16x8 pfh[4][2], pfl[4][2];
#pragma unroll
    for (int u = 0; u < 4; u++)
#pragma unroll
    for (int s = 0; s < 2; s++) {
        const float* pr = proj + (size_t)(wq * 64 + u * 16 + li) * DDIM + s * 32 + lg * 8;
        u16x8 hh, ll;
#pragma unroll
        for (int j = 0; j < 8; j++) {
            unsigned short h, l;
            split_hl(NORMC * pr[j], h, l);
            hh[j] = h; ll[j] = l;
        }
        pfh[u][s] = __builtin_bit_cast(bf16x8, hh);
        pfl[u][s] = __builtin_bit_cast(bf16x8, ll);
    }
    // ctx^T A-frags for swapped GEMM3: e-row = wq*16+li, k = m (8 chunks of 32)
    bf16x8 axh[8], axl[8];
#pragma unroll
    for (int mc = 0; mc < 8; mc++) {
        u16x8 hh, ll;
#pragma unroll
        for (int jj = 0; jj < 8; jj++) {
            float cvv = ctx[((size_t)g * 256 + mc * 32 + lg * 8 + jj) * 64 + wq * 16 + li];
            unsigned short h, l;
            split_hl(cvv, h, l);
            hh[jj] = h; ll[jj] = l;
        }
        axh[mc] = __builtin_bit_cast(bf16x8, hh);
        axl[mc] = __builtin_bit_cast(bf16x8, ll);
    }
    float ksm[4];
#pragma unroll
    for (int u = 0; u < 4; u++) ksm[u] = ksum[(size_t)g * 256 + wq * 64 + u * 16 + li];

    const int stg_n = t >> 3;
    const int stg_c = t & 7;
    const int r_begin = slice * (NSEQ / 16);

    float4 qa0, qa1;
    auto load_tile = [&](int r0) {
        const float4* qb = (const float4*)(qq + ((size_t)g * NSEQ + r0 + stg_n) * DDIM + stg_c * 8);
        qa0 = qb[0]; qa1 = qb[1];
    };
    auto stage_tile = [&](int b) {
        float qe[8] = {qa0.x,qa0.y,qa0.z,qa0.w,qa1.x,qa1.y,qa1.z,qa1.w};
        float sq = 0.f;
#pragma unroll
        for (int j = 0; j < 8; j++) sq += qe[j] * qe[j];
        sq += __shfl_xor(sq, 1); sq += __shfl_xor(sq, 2); sq += __shfl_xor(sq, 4);
        if (stg_c == 0) diag[b][stg_n] = 0.0625f * sq;
        u16x8 h8, l8;
#pragma unroll
        for (int j = 0; j < 8; j++) {
            unsigned short h, l;
            split_hl(qe[j], h, l);
            h8[j] = h; l8[j] = l;
        }
        int idx = stg_n * 64 + (stg_c ^ (stg_n & 7)) * 8;
        *(u16x8*)&QAR[b][idx] = h8;
        *(u16x8*)&QAR[b][2048 + idx] = l8;
    };

    load_tile(r_begin);
    stage_tile(0);
    __syncthreads();
    int cur = 0;
    for (int it = 0; it < 8; ++it) {
        if (it + 1 < 8) load_tile(r_begin + (it + 1) * 32);
        // GEMM1: dash_q
        f32x4 dacc[2][4];
#pragma unroll
        for (int tt = 0; tt < 2; tt++)
#pragma unroll
        for (int u = 0; u < 4; u++) dacc[tt][u] = zero4();
#pragma unroll
        for (int tt = 0; tt < 2; tt++)
#pragma unroll
        for (int s = 0; s < 2; s++) {
            int idx = (tt * 16 + li) * 64 + ((s * 4 + lg) ^ (li & 7)) * 8;
            bf16x8 ah = ldfrag(&QAR[cur][idx]);
            bf16x8 al = ldfrag(&QAR[cur][2048 + idx]);
#pragma unroll
            for (int u = 0; u < 4; u++) dacc[tt][u] = mfma3(ah, al, pfh[u][s], pfl[u][s], dacc[tt][u]);
        }
        // row-max partials over this wave's m-quarter
#pragma unroll
        for (int tt = 0; tt < 2; tt++)
#pragma unroll
        for (int r = 0; r < 4; r++) {
            float v = fmaxf(fmaxf(dacc[tt][0][r], dacc[tt][1][r]),
                            fmaxf(dacc[tt][2][r], dacc[tt][3][r]));
            v = fmaxf(v, __shfl_xor(v, 1));
            v = fmaxf(v, __shfl_xor(v, 2));
            v = fmaxf(v, __shfl_xor(v, 4));
            v = fmaxf(v, __shfl_xor(v, 8));
            if (li == 0) rmax4[wq][tt * 16 + lg * 4 + r] = v;
        }
        __syncthreads();   // B
        // qp phase: single-bf16 qp (den from the SAME rounded value), write qph
        float dl[2][4] = {{0.f,0.f,0.f,0.f},{0.f,0.f,0.f,0.f}};
#pragma unroll
        for (int tt = 0; tt < 2; tt++) {
            float cb[4];
#pragma unroll
            for (int r = 0; r < 4; r++) {
                int n = tt * 16 + lg * 4 + r;
                cb[r] = diag[cur][n] + fmaxf(fmaxf(rmax4[0][n], rmax4[1][n]),
                                             fmaxf(rmax4[2][n], rmax4[3][n]));
            }
#pragma unroll
            for (int u = 0; u < 4; u++)
#pragma unroll
            for (int r = 0; r < 4; r++) {
                float qp = __expf(dacc[tt][u][r] - cb[r]) + EPSC;
                unsigned short hb = rne16(qp);
                dl[tt][r] += __uint_as_float((unsigned)hb << 16) * ksm[u];
                int n = tt * 16 + lg * 4 + r;
                int mg = wq * 64 + u * 16 + li;
                qph[n * 256 + (((mg >> 3) ^ (n & 7)) << 3) + (mg & 7)] = hb;
            }
        }
#pragma unroll
        for (int tt = 0; tt < 2; tt++)
#pragma unroll
        for (int r = 0; r < 4; r++) {
            float v = dl[tt][r];
            v += __shfl_xor(v, 1); v += __shfl_xor(v, 2);
            v += __shfl_xor(v, 4); v += __shfl_xor(v, 8);
            if (li == 0) denp[wq][tt * 16 + lg * 4 + r] = v;
        }
        if (it + 1 < 8) stage_tile(cur ^ 1);
        __syncthreads();   // C
        // GEMM3 swapped: out^T[e][n] = ctx^T · qp^T, full m contraction per wave
        f32x4 oacc[2] = {zero4(), zero4()};
#pragma unroll
        for (int tt = 0; tt < 2; tt++) {
            int n = tt * 16 + li;
#pragma unroll
            for (int mc = 0; mc < 8; mc++) {
                bf16x8 b = ldfrag(&qph[n * 256 + (((mc * 4 + lg) ^ (li & 7)) << 3)]);
                oacc[tt] = __builtin_amdgcn_mfma_f32_16x16x32_bf16(axh[mc], b, oacc[tt], 0, 0, 0);
                oacc[tt] = __builtin_amdgcn_mfma_f32_16x16x32_bf16(axl[mc], b, oacc[tt], 0, 0, 0);
            }
        }
        // normalize + direct store: row n = tt*16+li, e = wq*16 + lg*4 + r
#pragma unroll
        for (int tt = 0; tt < 2; tt++) {
            int n = tt * 16 + li;
            float den = denp[0][n] + denp[1][n] + denp[2][n] + denp[3][n];
            float dinv = 1.0f / den;
            f32x4 o;
            o[0] = oacc[tt][0] * dinv; o[1] = oacc[tt][1] * dinv;
            o[2] = oacc[tt][2] * dinv; o[3] = oacc[tt][3] * dinv;
            float* op = outp + ((size_t)g * NSEQ + r_begin + it * 32 + n) * DDIM + wq * 16 + lg * 4;
            *(f32x4*)op = o;
        }
        cur ^= 1;
    }
}

extern "C" void kernel_launch(void* const* d_in, const int* in_sizes, int n_in,
                              void* d_out, int out_size, void* d_ws, size_t ws_size,
                              hipStream_t stream)
{
    const float* q    = (const float*)d_in[0];
    const float* k    = (const float*)d_in[1];
    const float* v    = (const float*)d_in[2];
    const float* proj = (const float*)d_in[3];
    float* outp = (float*)d_out;

    size_t per_ns = (size_t)GH * 16384 + (size_t)GH * 256 + (size_t)GH * 64;
    size_t fixed  = (size_t)GH * 16384 + (size_t)GH * 256;
    size_t need8  = 256 + 4 * (8 * per_ns + fixed);
    int ns = (ws_size >= need8) ? 8 : 1;

    unsigned* mxk = (unsigned*)d_ws;
    float* Apart  = (float*)((char*)d_ws + 256);
    float* Aspart = Apart  + (size_t)GH * ns * 16384;
    float* Svpart = Aspart + (size_t)GH * ns * 256;
    float* ctx    = Svpart + (size_t)GH * ns * 64;
    float* ksum   = ctx    + (size_t)GH * 16384;

    if (ns == 8) {
        hipMemsetAsync(d_ws, 0, 256, stream);
        kernA<8><<<dim3(8, GH), 256, 0, stream>>>(k, v, proj, Apart, Aspart, Svpart, mxk);
    } else {
        hipMemsetAsync(d_ws, 0, 256 + 4 * per_ns, stream);
        kernA<1><<<dim3(8, GH), 256, 0, stream>>>(k, v, proj, Apart, Aspart, Svpart, mxk);
    }
    kernB<<<dim3(16, GH), 256, 0, stream>>>(Apart, Aspart, Svpart, mxk, ctx, ksum, ns);
    kernC<<<dim3(16, GH), 256, 0, stream>>>(q, proj, ctx, ksum, outp);
}